// Round 9
// baseline (180.504 us; speedup 1.0000x reference)
//
#include <hip/hip_runtime.h>
#include <hip/hip_bf16.h>

// F2VConv3d: per-face double-GEMM (both on MFMA) then lightweight vertex gather.
//   W[f,:] = fc[f,:] @ sw          (MFMA1, K=16 padded to 32, computed as W^T)
//   feat[f,cm] = inp[f,cm>>1] * W[f,cm]   (fused epilogue, direct-global inp)
//   g[f] = feat[f,:] @ dw          (MFMA2)
//   out[v] = BN(relu(mean_{f in N(v)} g[f] + bias))
// R8: k_faceg de-serialized: no s_inpb (epilogue reads inp as float2 direct
// from global, issued early), LDS 33.8KB -> 4 blocks/CU, ONE tile per block
// (grid=3125) -> 3 barriers/tile, no persistent-loop tail. k_gather GB=1024.

constexpr int C_IN  = 128;
constexpr int KF    = 16;
constexpr int CM    = 256;    // C_IN * MULT
constexpr int C_OUT = 128;
constexpr int CAP   = 32;     // max tracked faces per vertex
constexpr int GB    = 1024;   // k_gather grid (k_red loops over GB)
constexpr int FT    = 64;     // faces per k_faceg tile
constexpr int FP    = 264;    // feat pitch (u16): 528B rows
constexpr int OPW   = 132;    // out staging pitch (f32 words): 528B
constexpr float BN_EPS = 1e-3f;

typedef __attribute__((ext_vector_type(8))) short short8;
typedef __attribute__((ext_vector_type(4))) float f32x4;

__device__ __forceinline__ ushort f2bf(float x) {
  union { float f; unsigned u; } v; v.f = x;
  return (ushort)((v.u + 0x7fffu + ((v.u >> 16) & 1u)) >> 16);
}
__device__ __forceinline__ float b2f(ushort u) {
  return __uint_as_float((unsigned)u << 16);
}
// packed RNE f32x2 -> bf16x2 (v_cvt_pk_bf16_f32); low 16 bits = a
__device__ __forceinline__ uint pk2(float a, float b) {
  __hip_bfloat162 h = __float22bfloat162_rn(float2{a, b});
  return *(uint*)&h;
}

// dwt[n][k] = bf16(dw[k][n]) (MFMA2 B-frag order);
// swt[cm][k] = bf16(sw[k][cm]) padded K 16->32 (MFMA1 A-frag order).
__global__ __launch_bounds__(256) void k_prep(const float* __restrict__ dw,
                                              const float* __restrict__ sw,
                                              ushort* __restrict__ dwt,
                                              ushort* __restrict__ swt) {
  const int b = blockIdx.x, tid = threadIdx.x;
  if (b < 64) {                       // dwt: 128*256 elems, 2/thread
    int i = b * 512 + tid;
#pragma unroll
    for (int r = 0; r < 2; ++r, i += 256) {
      int n = i >> 8, k = i & 255;
      dwt[i] = f2bf(dw[k * C_OUT + n]);
    }
  } else {                            // swt: 256*32 elems, 1/thread
    int i = (b - 64) * 256 + tid;
    int cm = i >> 5, k = i & 31;
    swt[i] = (k < KF) ? f2bf(sw[k * CM + cm]) : (ushort)0;
  }
}

__global__ __launch_bounds__(256) void k_fill(
    const int* __restrict__ face, const int* __restrict__ vt_map,
    int* __restrict__ cnt, int* __restrict__ slots, int n_inc) {
  int i = blockIdx.x * blockDim.x + threadIdx.x;
  if (i < n_inc) {
    int f = i / 3;
    int v = vt_map[face[i]];
    int p = atomicAdd(&cnt[v], 1);
    if (p < CAP) slots[(size_t)v * CAP + p] = f;
  }
}

// One 64-face tile per block, 4 waves, 3 barriers.
// MFMA1: W^T[cm][face] = swt @ fc^T; fused epilogue multiplies by inp
// (float2 direct-global, loaded at tile start) -> feat bf16 in s_buf.
// MFMA2: g = feat @ dw. f32 staging aliased over s_buf (XOR-swizzled),
// packed bf16 g stores.
__global__ __launch_bounds__(256, 4) void k_faceg(
    const float* __restrict__ inp, const float* __restrict__ fc,
    const ushort* __restrict__ swt, const ushort* __restrict__ dwt,
    ushort* __restrict__ g) {
  __shared__ ushort s_buf[FT * FP];     // 33792 B  feat bf16, aliased staging
  float* s_outf = (float*)s_buf;

  const int tid  = threadIdx.x;
  const int w    = tid >> 6;        // wave -> cm range [w*64, w*64+64)
  const int lane = tid & 63;
  const int rm   = lane & 15;
  const int kg   = lane >> 4;
  const int fb   = blockIdx.x * FT;

  // epilogue inp values: iv[ft][ct] = inp[fb+ft*16+rm][2*(w*16+ct*4+kg) ..+1]
  // (kg lanes cover contiguous 32B per face row; ct pairs share 64B lines)
  float2 iv[4][4];
#pragma unroll
  for (int ft = 0; ft < 4; ++ft) {
    const float* rowp = &inp[(size_t)(fb + ft * 16 + rm) * C_IN];
#pragma unroll
    for (int ct = 0; ct < 4; ++ct)
      iv[ft][ct] = *(const float2*)&rowp[(w * 16 + ct * 4 + kg) * 2];
  }

  // MFMA1 A-frags: swt rows cm = w*64 + ct*16 + rm
  short8 a1[4];
#pragma unroll
  for (int ct = 0; ct < 4; ++ct)
    a1[ct] = *(const short8*)&swt[(size_t)(w * 64 + ct * 16 + rm) * 32 + kg * 8];

  // MFMA1 B-frags from fc (f32 global -> bf16 regs); kg>=2 lanes zero (K-pad)
  short8 b1[4];
#pragma unroll
  for (int ft = 0; ft < 4; ++ft) {
    const float* fr = &fc[(size_t)(fb + ft * 16 + rm) * KF + (kg & 1) * 8];
    const float4 p0 = *(const float4*)fr;
    const float4 p1 = *(const float4*)(fr + 4);
    uint4 u;
    u.x = pk2(p0.x, p0.y); u.y = pk2(p0.z, p0.w);
    u.z = pk2(p1.x, p1.y); u.w = pk2(p1.z, p1.w);
    if (kg >= 2) u = uint4{0, 0, 0, 0};
    b1[ft] = *(short8*)&u;
  }

  // MFMA1 + fused inp-multiply epilogue -> feat bf16 in s_buf
  // D layout (m89): col = lane&15 = face_local, row = kg*4+r = cm_local
#pragma unroll
  for (int ft = 0; ft < 4; ++ft) {
#pragma unroll
    for (int ct = 0; ct < 4; ++ct) {
      f32x4 acc = {0.f, 0.f, 0.f, 0.f};
      acc = __builtin_amdgcn_mfma_f32_16x16x32_bf16(a1[ct], b1[ft], acc, 0, 0, 0);
      const int face = ft * 16 + rm;
      const int cmb  = w * 64 + ct * 16 + kg * 4;   // multiple of 4
      const float i0 = iv[ft][ct].x;                // channel cmb>>1
      const float i1 = iv[ft][ct].y;                // channel (cmb>>1)+1
      uint2 pw;
      pw.x = pk2(acc[0] * i0, acc[1] * i0);
      pw.y = pk2(acc[2] * i1, acc[3] * i1);
      *(uint2*)&s_buf[face * FP + cmb] = pw;
    }
  }

  // MFMA2 B-frags (dwt, L2-hot), short live range
  short8 bfr[2][8];
#pragma unroll
  for (int nt = 0; nt < 2; ++nt) {
    const int n = (w * 2 + nt) * 16 + rm;
#pragma unroll
    for (int ks = 0; ks < 8; ++ks)
      bfr[nt][ks] = *(const short8*)&dwt[n * 256 + ks * 32 + kg * 8];
  }
  __syncthreads();                  // 1: feat ready

  f32x4 acc2[4][2];
#pragma unroll
  for (int fs = 0; fs < 4; ++fs)
#pragma unroll
    for (int nt = 0; nt < 2; ++nt)
      acc2[fs][nt] = (f32x4){0.f, 0.f, 0.f, 0.f};

#pragma unroll
  for (int fs = 0; fs < 4; ++fs)
#pragma unroll
    for (int ks = 0; ks < 8; ++ks) {
      const short8 af = *(const short8*)&s_buf[(fs * 16 + rm) * FP + ks * 32 + kg * 8];
      acc2[fs][0] = __builtin_amdgcn_mfma_f32_16x16x32_bf16(af, bfr[0][ks], acc2[fs][0], 0, 0, 0);
      acc2[fs][1] = __builtin_amdgcn_mfma_f32_16x16x32_bf16(af, bfr[1][ks], acc2[fs][1], 0, 0, 0);
    }
  __syncthreads();                  // 2: all feat reads done (alias!)

  // f32 staging, XOR-swizzled cols
#pragma unroll
  for (int fs = 0; fs < 4; ++fs)
#pragma unroll
    for (int nt = 0; nt < 2; ++nt)
#pragma unroll
      for (int r = 0; r < 4; ++r) {
        const int row = fs * 16 + kg * 4 + r;
        const int col = (w * 2 + nt) * 16 + rm;
        s_outf[row * OPW + (col ^ ((row & 7) << 2))] = acc2[fs][nt][r];
      }
  __syncthreads();                  // 3: staging ready

  // packed bf16 g stores: thread -> 1/4 row (32 channels)
  const int irow = tid >> 2;
  const int cb   = (tid & 3) * 32;
  const int sz   = (irow & 7) << 2;
#pragma unroll
  for (int i = 0; i < 4; ++i) {
    const float4 a = *(const float4*)&s_outf[irow * OPW + ((cb + 8 * i) ^ sz)];
    const float4 b = *(const float4*)&s_outf[irow * OPW + ((cb + 8 * i + 4) ^ sz)];
    uint4 u;
    u.x = pk2(a.x, a.y); u.y = pk2(a.z, a.w);
    u.z = pk2(b.x, b.y); u.w = pk2(b.z, b.w);
    *(short8*)&g[(size_t)(fb + irow) * C_OUT + cb + 8 * i] = *(short8*)&u;
  }
}

// 16 verts/tile, 16 threads/vert. Partials written TRANSPOSED: part[col][GB].
__global__ __launch_bounds__(256) void k_gather(
    const ushort* __restrict__ g, const int* __restrict__ cnt,
    const int* __restrict__ slots, const int* __restrict__ nf_cnt,
    const float* __restrict__ bias, float* __restrict__ out,
    float* __restrict__ part, int nv, int ntiles) {
  __shared__ int   s_slots[16][CAP];
  __shared__ int   s_deg[16];
  __shared__ float s_red[256][8];

  const int tid = threadIdx.x;
  const int q   = tid & 15;
  const int vg  = tid >> 4;
  const int c8  = q * 8;

  float bs[8];
#pragma unroll
  for (int j = 0; j < 8; ++j) bs[j] = bias[c8 + j];
  float st_s[8], st_q[8];
#pragma unroll
  for (int j = 0; j < 8; ++j) { st_s[j] = 0.f; st_q[j] = 0.f; }

  for (int tile = blockIdx.x; tile < ntiles; tile += gridDim.x) {
    const int vbase = tile * 16;
    __syncthreads();
    for (int i = tid; i < 16 * CAP; i += 256)
      s_slots[i >> 5][i & 31] = slots[((size_t)vbase << 5) + i];
    if (tid < 16) {
      int d = cnt[vbase + tid];
      s_deg[tid] = d > CAP ? CAP : d;
    }
    __syncthreads();

    const int v = vbase + vg;
    float a[8];
#pragma unroll
    for (int j = 0; j < 8; ++j) a[j] = 0.f;
    const int deg = s_deg[vg];
    int t = 0;
    for (; t + 2 <= deg; t += 2) {
      const int f0 = s_slots[vg][t], f1 = s_slots[vg][t + 1];
      const short8 r0 = *(const short8*)&g[(size_t)f0 * C_OUT + c8];
      const short8 r1 = *(const short8*)&g[(size_t)f1 * C_OUT + c8];
#pragma unroll
      for (int j = 0; j < 8; ++j)
        a[j] += b2f((ushort)r0[j]) + b2f((ushort)r1[j]);
    }
    if (t < deg) {
      const short8 r0 = *(const short8*)&g[(size_t)s_slots[vg][t] * C_OUT + c8];
#pragma unroll
      for (int j = 0; j < 8; ++j) a[j] += b2f((ushort)r0[j]);
    }

    int d = nf_cnt[v]; if (d < 1) d = 1;
    const float inv = 1.0f / (float)d;
    float r[8];
#pragma unroll
    for (int j = 0; j < 8; ++j) {
      r[j] = fmaxf(fmaf(a[j], inv, bs[j]), 0.f);
      st_s[j] += r[j];
      st_q[j] = fmaf(r[j], r[j], st_q[j]);
    }
    *(float4*)&out[(size_t)v * C_OUT + c8]     = make_float4(r[0], r[1], r[2], r[3]);
    *(float4*)&out[(size_t)v * C_OUT + c8 + 4] = make_float4(r[4], r[5], r[6], r[7]);
  }

  __syncthreads();
#pragma unroll
  for (int j = 0; j < 8; ++j) s_red[tid][j] = st_s[j];
  __syncthreads();
  if (tid < 16) {
    for (int j = 0; j < 8; ++j) {
      float x = 0.f;
      for (int gg = 0; gg < 16; ++gg) x += s_red[gg * 16 + tid][j];
      part[(size_t)(tid * 8 + j) * GB + blockIdx.x] = x;           // transposed
    }
  }
  __syncthreads();
#pragma unroll
  for (int j = 0; j < 8; ++j) s_red[tid][j] = st_q[j];
  __syncthreads();
  if (tid < 16) {
    for (int j = 0; j < 8; ++j) {
      float x = 0.f;
      for (int gg = 0; gg < 16; ++gg) x += s_red[gg * 16 + tid][j];
      part[(size_t)(128 + tid * 8 + j) * GB + blockIdx.x] = x;     // transposed
    }
  }
}

// 256 blocks: block j reduces part[j][0:GB] (coalesced) -> red[j].
__global__ __launch_bounds__(256) void k_red(const float* __restrict__ part,
                                             float* __restrict__ red) {
  const int j   = blockIdx.x;
  const int tid = threadIdx.x;
  float v = 0.f;
#pragma unroll
  for (int b = 0; b < GB; b += 256) v += part[(size_t)j * GB + b + tid];
#pragma unroll
  for (int off = 32; off > 0; off >>= 1) v += __shfl_down(v, off);
  __shared__ float sred[4];
  if ((tid & 63) == 0) sred[tid >> 6] = v;
  __syncthreads();
  if (tid == 0) red[j] = sred[0] + sred[1] + sred[2] + sred[3];
}

__global__ void k_fin(const float* __restrict__ red,
                      const float* __restrict__ gamma, const float* __restrict__ beta,
                      float* __restrict__ scale, float* __restrict__ shift, float invN) {
  int o = threadIdx.x;   // 128
  float mean = red[o] * invN;
  float var  = red[128 + o] * invN - mean * mean;
  float sc   = gamma[o] * rsqrtf(var + BN_EPS);
  scale[o] = sc;
  shift[o] = fmaf(-mean, sc, beta[o]);
}

__global__ __launch_bounds__(256) void k_bn(float* __restrict__ out,
                                            const float* __restrict__ scale,
                                            const float* __restrict__ shift, int n4) {
  int idx = blockIdx.x * blockDim.x + threadIdx.x;
  int stride = gridDim.x * blockDim.x;
  for (; idx < n4; idx += stride) {
    float4 v = ((const float4*)out)[idx];
    int base = (idx * 4) & (C_OUT - 1);
    float4 sc = *(const float4*)&scale[base];
    float4 sh = *(const float4*)&shift[base];
    v.x = fmaf(v.x, sc.x, sh.x);
    v.y = fmaf(v.y, sc.y, sh.y);
    v.z = fmaf(v.z, sc.z, sh.z);
    v.w = fmaf(v.w, sc.w, sh.w);
    ((float4*)out)[idx] = v;
  }
}

extern "C" void kernel_launch(void* const* d_in, const int* in_sizes, int n_in,
                              void* d_out, int out_size, void* d_ws, size_t ws_size,
                              hipStream_t stream) {
  const float* inputs = (const float*)d_in[0];
  const float* fc     = (const float*)d_in[1];
  const int*   face   = (const int*)d_in[2];
  const int*   nf_cnt = (const int*)d_in[3];
  const int*   vt_map = (const int*)d_in[4];
  const float* sw     = (const float*)d_in[5];
  const float* dw     = (const float*)d_in[6];
  const float* bias   = (const float*)d_in[7];
  const float* gamma  = (const float*)d_in[8];
  const float* beta   = (const float*)d_in[9];
  float* out = (float*)d_out;

  const int nf = in_sizes[0] / C_IN;   // 200000
  const int nv = in_sizes[3];          // 100000

  // ws: cnt[nv] | scale[128] | shift[128] | red[256] | part[256*GB]
  //     | dwt[128*256 u16] | swt[256*32 u16] | slots[nv*CAP] | g[nf*128 u16]
  char* p = (char*)d_ws;
  int*    cnt   = (int*)p;            p += (size_t)nv * 4;
  float*  scale = (float*)p;          p += C_OUT * 4;
  float*  shift = (float*)p;          p += C_OUT * 4;
  float*  red   = (float*)p;          p += 256 * 4;
  float*  part  = (float*)p;          p += (size_t)256 * GB * 4;
  ushort* dwt   = (ushort*)p;         p += (size_t)C_OUT * CM * 2;
  ushort* swt   = (ushort*)p;         p += (size_t)CM * 32 * 2;
  int*    slots = (int*)p;            p += (size_t)nv * CAP * 4;
  ushort* g     = (ushort*)p;

  hipMemsetAsync(cnt, 0, (size_t)nv * 4, stream);

  k_prep<<<96, 256, 0, stream>>>(dw, sw, dwt, swt);

  const int n_inc = nf * 3;
  k_fill<<<(n_inc + 255) / 256, 256, 0, stream>>>(face, vt_map, cnt, slots, n_inc);

  const int ntiles_f = (nf + FT - 1) / FT;   // 3125 (one tile per block)
  k_faceg<<<ntiles_f, 256, 0, stream>>>(inputs, fc, swt, dwt, g);

  const int ntiles_v = (nv + 15) / 16;       // 6250
  k_gather<<<GB, 256, 0, stream>>>(g, cnt, slots, nf_cnt, bias, out, part, nv, ntiles_v);

  k_red<<<256, 256, 0, stream>>>(part, red);
  k_fin<<<1, 128, 0, stream>>>(red, gamma, beta, scale, shift, 1.0f / (float)nv);

  const int n4 = (nv * C_OUT) / 4;
  k_bn<<<4096, 256, 0, stream>>>(out, scale, shift, n4);
}

// Round 10
// 172.800 us; speedup vs baseline: 1.0446x; 1.0446x over previous
//
#include <hip/hip_runtime.h>
#include <hip/hip_bf16.h>

// F2VConv3d: per-face double-GEMM (both on MFMA) then lightweight vertex gather.
//   W[f,:] = fc[f,:] @ sw          (MFMA1, K=16 padded to 32, computed as W^T)
//   feat[f,cm] = inp[f,cm>>1] * W[f,cm]   (fused epilogue, direct-global inp)
//   g[f] = feat[f,:] @ dw          (MFMA2)
//   out[v] = BN(relu(mean_{f in N(v)} g[f] + bias))
// R9: (a) k_faceg: sched_barrier(0) pins iv/a1/b1 prefetch (R8: compiler sank
//     the 16 iv loads into the epilogue -> serial 700cyc chains, VGPR=52).
//     (b) k_gather: no LDS staging in tile loop (slots/cnt via lane-broadcast
//     reads, int4 slot quads, 4-deep g-row ILP) -> zero barriers per tile.

constexpr int C_IN  = 128;
constexpr int KF    = 16;
constexpr int CM    = 256;    // C_IN * MULT
constexpr int C_OUT = 128;
constexpr int CAP   = 32;     // max tracked faces per vertex
constexpr int GB    = 1024;   // k_gather grid (k_red loops over GB)
constexpr int FT    = 64;     // faces per k_faceg tile
constexpr int FP    = 264;    // feat pitch (u16): 528B rows
constexpr int OPW   = 132;    // out staging pitch (f32 words): 528B
constexpr float BN_EPS = 1e-3f;

typedef __attribute__((ext_vector_type(8))) short short8;
typedef __attribute__((ext_vector_type(4))) float f32x4;

__device__ __forceinline__ ushort f2bf(float x) {
  union { float f; unsigned u; } v; v.f = x;
  return (ushort)((v.u + 0x7fffu + ((v.u >> 16) & 1u)) >> 16);
}
__device__ __forceinline__ float b2f(ushort u) {
  return __uint_as_float((unsigned)u << 16);
}
// packed RNE f32x2 -> bf16x2 (v_cvt_pk_bf16_f32); low 16 bits = a
__device__ __forceinline__ uint pk2(float a, float b) {
  __hip_bfloat162 h = __float22bfloat162_rn(float2{a, b});
  return *(uint*)&h;
}

// dwt[n][k] = bf16(dw[k][n]) (MFMA2 B-frag order);
// swt[cm][k] = bf16(sw[k][cm]) padded K 16->32 (MFMA1 A-frag order).
__global__ __launch_bounds__(256) void k_prep(const float* __restrict__ dw,
                                              const float* __restrict__ sw,
                                              ushort* __restrict__ dwt,
                                              ushort* __restrict__ swt) {
  const int b = blockIdx.x, tid = threadIdx.x;
  if (b < 64) {                       // dwt: 128*256 elems, 2/thread
    int i = b * 512 + tid;
#pragma unroll
    for (int r = 0; r < 2; ++r, i += 256) {
      int n = i >> 8, k = i & 255;
      dwt[i] = f2bf(dw[k * C_OUT + n]);
    }
  } else {                            // swt: 256*32 elems, 1/thread
    int i = (b - 64) * 256 + tid;
    int cm = i >> 5, k = i & 31;
    swt[i] = (k < KF) ? f2bf(sw[k * CM + cm]) : (ushort)0;
  }
}

__global__ __launch_bounds__(256) void k_fill(
    const int* __restrict__ face, const int* __restrict__ vt_map,
    int* __restrict__ cnt, int* __restrict__ slots, int n_inc) {
  int i = blockIdx.x * blockDim.x + threadIdx.x;
  if (i < n_inc) {
    int f = i / 3;
    int v = vt_map[face[i]];
    int p = atomicAdd(&cnt[v], 1);
    if (p < CAP) slots[(size_t)v * CAP + p] = f;
  }
}

// One 64-face tile per block, 4 waves, 3 barriers.
__global__ __launch_bounds__(256, 4) void k_faceg(
    const float* __restrict__ inp, const float* __restrict__ fc,
    const ushort* __restrict__ swt, const ushort* __restrict__ dwt,
    ushort* __restrict__ g) {
  __shared__ ushort s_buf[FT * FP];     // 33792 B  feat bf16, aliased staging
  float* s_outf = (float*)s_buf;

  const int tid  = threadIdx.x;
  const int w    = tid >> 6;        // wave -> cm range [w*64, w*64+64)
  const int lane = tid & 63;
  const int rm   = lane & 15;
  const int kg   = lane >> 4;
  const int fb   = blockIdx.x * FT;

  // epilogue inp values: iv[ft][ct] = inp[fb+ft*16+rm][2*(w*16+ct*4+kg) ..+1]
  float2 iv[4][4];
#pragma unroll
  for (int ft = 0; ft < 4; ++ft) {
    const float* rowp = &inp[(size_t)(fb + ft * 16 + rm) * C_IN];
#pragma unroll
    for (int ct = 0; ct < 4; ++ct)
      iv[ft][ct] = *(const float2*)&rowp[(w * 16 + ct * 4 + kg) * 2];
  }

  // MFMA1 A-frags: swt rows cm = w*64 + ct*16 + rm
  short8 a1[4];
#pragma unroll
  for (int ct = 0; ct < 4; ++ct)
    a1[ct] = *(const short8*)&swt[(size_t)(w * 64 + ct * 16 + rm) * 32 + kg * 8];

  // MFMA1 B-frags from fc (f32 global -> bf16 regs); kg>=2 lanes zero (K-pad)
  short8 b1[4];
#pragma unroll
  for (int ft = 0; ft < 4; ++ft) {
    const float* fr = &fc[(size_t)(fb + ft * 16 + rm) * KF + (kg & 1) * 8];
    const float4 p0 = *(const float4*)fr;
    const float4 p1 = *(const float4*)(fr + 4);
    uint4 u;
    u.x = pk2(p0.x, p0.y); u.y = pk2(p0.z, p0.w);
    u.z = pk2(p1.x, p1.y); u.w = pk2(p1.z, p1.w);
    if (kg >= 2) u = uint4{0, 0, 0, 0};
    b1[ft] = *(short8*)&u;
  }

  // Pin all prefetch loads above this point: forbid the scheduler from
  // sinking iv/a1/b1 into the epilogue (R8 failure: serial load chains).
  __builtin_amdgcn_sched_barrier(0);

  // MFMA1 + fused inp-multiply epilogue -> feat bf16 in s_buf
  // D layout (m89): col = lane&15 = face_local, row = kg*4+r = cm_local
#pragma unroll
  for (int ft = 0; ft < 4; ++ft) {
#pragma unroll
    for (int ct = 0; ct < 4; ++ct) {
      f32x4 acc = {0.f, 0.f, 0.f, 0.f};
      acc = __builtin_amdgcn_mfma_f32_16x16x32_bf16(a1[ct], b1[ft], acc, 0, 0, 0);
      const int face = ft * 16 + rm;
      const int cmb  = w * 64 + ct * 16 + kg * 4;   // multiple of 4
      const float i0 = iv[ft][ct].x;                // channel cmb>>1
      const float i1 = iv[ft][ct].y;                // channel (cmb>>1)+1
      uint2 pw;
      pw.x = pk2(acc[0] * i0, acc[1] * i0);
      pw.y = pk2(acc[2] * i1, acc[3] * i1);
      *(uint2*)&s_buf[face * FP + cmb] = pw;
    }
  }

  // MFMA2 B-frags (dwt, L2-hot), short live range
  short8 bfr[2][8];
#pragma unroll
  for (int nt = 0; nt < 2; ++nt) {
    const int n = (w * 2 + nt) * 16 + rm;
#pragma unroll
    for (int ks = 0; ks < 8; ++ks)
      bfr[nt][ks] = *(const short8*)&dwt[n * 256 + ks * 32 + kg * 8];
  }
  __syncthreads();                  // 1: feat ready

  f32x4 acc2[4][2];
#pragma unroll
  for (int fs = 0; fs < 4; ++fs)
#pragma unroll
    for (int nt = 0; nt < 2; ++nt)
      acc2[fs][nt] = (f32x4){0.f, 0.f, 0.f, 0.f};

#pragma unroll
  for (int fs = 0; fs < 4; ++fs)
#pragma unroll
    for (int ks = 0; ks < 8; ++ks) {
      const short8 af = *(const short8*)&s_buf[(fs * 16 + rm) * FP + ks * 32 + kg * 8];
      acc2[fs][0] = __builtin_amdgcn_mfma_f32_16x16x32_bf16(af, bfr[0][ks], acc2[fs][0], 0, 0, 0);
      acc2[fs][1] = __builtin_amdgcn_mfma_f32_16x16x32_bf16(af, bfr[1][ks], acc2[fs][1], 0, 0, 0);
    }
  __syncthreads();                  // 2: all feat reads done (alias!)

  // f32 staging, XOR-swizzled cols
#pragma unroll
  for (int fs = 0; fs < 4; ++fs)
#pragma unroll
    for (int nt = 0; nt < 2; ++nt)
#pragma unroll
      for (int r = 0; r < 4; ++r) {
        const int row = fs * 16 + kg * 4 + r;
        const int col = (w * 2 + nt) * 16 + rm;
        s_outf[row * OPW + (col ^ ((row & 7) << 2))] = acc2[fs][nt][r];
      }
  __syncthreads();                  // 3: staging ready

  // packed bf16 g stores: thread -> 1/4 row (32 channels)
  const int irow = tid >> 2;
  const int cb   = (tid & 3) * 32;
  const int sz   = (irow & 7) << 2;
#pragma unroll
  for (int i = 0; i < 4; ++i) {
    const float4 a = *(const float4*)&s_outf[irow * OPW + ((cb + 8 * i) ^ sz)];
    const float4 b = *(const float4*)&s_outf[irow * OPW + ((cb + 8 * i + 4) ^ sz)];
    uint4 u;
    u.x = pk2(a.x, a.y); u.y = pk2(a.z, a.w);
    u.z = pk2(b.x, b.y); u.w = pk2(b.z, b.w);
    *(short8*)&g[(size_t)(fb + irow) * C_OUT + cb + 8 * i] = *(short8*)&u;
  }
}

// 16 verts/tile, 16 threads/vert, NO per-tile LDS/barriers: slots & cnt read
// via 16-lane broadcast, int4 slot quads, 4-deep g-row load ILP.
__global__ __launch_bounds__(256) void k_gather(
    const ushort* __restrict__ g, const int* __restrict__ cnt,
    const int* __restrict__ slots, const int* __restrict__ nf_cnt,
    const float* __restrict__ bias, float* __restrict__ out,
    float* __restrict__ part, int nv, int ntiles) {
  __shared__ float s_red[256][8];

  const int tid = threadIdx.x;
  const int q   = tid & 15;
  const int vg  = tid >> 4;
  const int c8  = q * 8;

  float bs[8];
#pragma unroll
  for (int j = 0; j < 8; ++j) bs[j] = bias[c8 + j];
  float st_s[8], st_q[8];
#pragma unroll
  for (int j = 0; j < 8; ++j) { st_s[j] = 0.f; st_q[j] = 0.f; }

  for (int tile = blockIdx.x; tile < ntiles; tile += gridDim.x) {
    const int v = tile * 16 + vg;
    int deg = cnt[v]; deg = deg > CAP ? CAP : deg;      // lane-broadcast
    const int* sl = &slots[(size_t)v * CAP];

    float a[8];
#pragma unroll
    for (int j = 0; j < 8; ++j) a[j] = 0.f;

    int t = 0;
    for (; t + 4 <= deg; t += 4) {
      const int4 ff = *(const int4*)&sl[t];             // broadcast 16B
      const short8 r0 = *(const short8*)&g[(size_t)ff.x * C_OUT + c8];
      const short8 r1 = *(const short8*)&g[(size_t)ff.y * C_OUT + c8];
      const short8 r2 = *(const short8*)&g[(size_t)ff.z * C_OUT + c8];
      const short8 r3 = *(const short8*)&g[(size_t)ff.w * C_OUT + c8];
#pragma unroll
      for (int j = 0; j < 8; ++j)
        a[j] += (b2f((ushort)r0[j]) + b2f((ushort)r1[j]))
              + (b2f((ushort)r2[j]) + b2f((ushort)r3[j]));
    }
    for (; t < deg; ++t) {
      const short8 r0 = *(const short8*)&g[(size_t)sl[t] * C_OUT + c8];
#pragma unroll
      for (int j = 0; j < 8; ++j) a[j] += b2f((ushort)r0[j]);
    }

    int d = nf_cnt[v]; if (d < 1) d = 1;
    const float inv = 1.0f / (float)d;
    float r[8];
#pragma unroll
    for (int j = 0; j < 8; ++j) {
      r[j] = fmaxf(fmaf(a[j], inv, bs[j]), 0.f);
      st_s[j] += r[j];
      st_q[j] = fmaf(r[j], r[j], st_q[j]);
    }
    *(float4*)&out[(size_t)v * C_OUT + c8]     = make_float4(r[0], r[1], r[2], r[3]);
    *(float4*)&out[(size_t)v * C_OUT + c8 + 4] = make_float4(r[4], r[5], r[6], r[7]);
  }

  // deterministic block partials: part[col][GB] (transposed)
#pragma unroll
  for (int j = 0; j < 8; ++j) s_red[tid][j] = st_s[j];
  __syncthreads();
  if (tid < 16) {
    for (int j = 0; j < 8; ++j) {
      float x = 0.f;
      for (int gg = 0; gg < 16; ++gg) x += s_red[gg * 16 + tid][j];
      part[(size_t)(tid * 8 + j) * GB + blockIdx.x] = x;
    }
  }
  __syncthreads();
#pragma unroll
  for (int j = 0; j < 8; ++j) s_red[tid][j] = st_q[j];
  __syncthreads();
  if (tid < 16) {
    for (int j = 0; j < 8; ++j) {
      float x = 0.f;
      for (int gg = 0; gg < 16; ++gg) x += s_red[gg * 16 + tid][j];
      part[(size_t)(128 + tid * 8 + j) * GB + blockIdx.x] = x;
    }
  }
}

// 256 blocks: block j reduces part[j][0:GB] (coalesced) -> red[j].
__global__ __launch_bounds__(256) void k_red(const float* __restrict__ part,
                                             float* __restrict__ red) {
  const int j   = blockIdx.x;
  const int tid = threadIdx.x;
  float v = 0.f;
#pragma unroll
  for (int b = 0; b < GB; b += 256) v += part[(size_t)j * GB + b + tid];
#pragma unroll
  for (int off = 32; off > 0; off >>= 1) v += __shfl_down(v, off);
  __shared__ float sred[4];
  if ((tid & 63) == 0) sred[tid >> 6] = v;
  __syncthreads();
  if (tid == 0) red[j] = sred[0] + sred[1] + sred[2] + sred[3];
}

__global__ void k_fin(const float* __restrict__ red,
                      const float* __restrict__ gamma, const float* __restrict__ beta,
                      float* __restrict__ scale, float* __restrict__ shift, float invN) {
  int o = threadIdx.x;   // 128
  float mean = red[o] * invN;
  float var  = red[128 + o] * invN - mean * mean;
  float sc   = gamma[o] * rsqrtf(var + BN_EPS);
  scale[o] = sc;
  shift[o] = fmaf(-mean, sc, beta[o]);
}

__global__ __launch_bounds__(256) void k_bn(float* __restrict__ out,
                                            const float* __restrict__ scale,
                                            const float* __restrict__ shift, int n4) {
  int idx = blockIdx.x * blockDim.x + threadIdx.x;
  int stride = gridDim.x * blockDim.x;
  for (; idx < n4; idx += stride) {
    float4 v = ((const float4*)out)[idx];
    int base = (idx * 4) & (C_OUT - 1);
    float4 sc = *(const float4*)&scale[base];
    float4 sh = *(const float4*)&shift[base];
    v.x = fmaf(v.x, sc.x, sh.x);
    v.y = fmaf(v.y, sc.y, sh.y);
    v.z = fmaf(v.z, sc.z, sh.z);
    v.w = fmaf(v.w, sc.w, sh.w);
    ((float4*)out)[idx] = v;
  }
}

extern "C" void kernel_launch(void* const* d_in, const int* in_sizes, int n_in,
                              void* d_out, int out_size, void* d_ws, size_t ws_size,
                              hipStream_t stream) {
  const float* inputs = (const float*)d_in[0];
  const float* fc     = (const float*)d_in[1];
  const int*   face   = (const int*)d_in[2];
  const int*   nf_cnt = (const int*)d_in[3];
  const int*   vt_map = (const int*)d_in[4];
  const float* sw     = (const float*)d_in[5];
  const float* dw     = (const float*)d_in[6];
  const float* bias   = (const float*)d_in[7];
  const float* gamma  = (const float*)d_in[8];
  const float* beta   = (const float*)d_in[9];
  float* out = (float*)d_out;

  const int nf = in_sizes[0] / C_IN;   // 200000
  const int nv = in_sizes[3];          // 100000

  // ws: cnt[nv] | scale[128] | shift[128] | red[256] | part[256*GB]
  //     | dwt[128*256 u16] | swt[256*32 u16] | slots[nv*CAP] | g[nf*128 u16]
  char* p = (char*)d_ws;
  int*    cnt   = (int*)p;            p += (size_t)nv * 4;
  float*  scale = (float*)p;          p += C_OUT * 4;
  float*  shift = (float*)p;          p += C_OUT * 4;
  float*  red   = (float*)p;          p += 256 * 4;
  float*  part  = (float*)p;          p += (size_t)256 * GB * 4;
  ushort* dwt   = (ushort*)p;         p += (size_t)C_OUT * CM * 2;
  ushort* swt   = (ushort*)p;         p += (size_t)CM * 32 * 2;
  int*    slots = (int*)p;            p += (size_t)nv * CAP * 4;
  ushort* g     = (ushort*)p;

  hipMemsetAsync(cnt, 0, (size_t)nv * 4, stream);

  k_prep<<<96, 256, 0, stream>>>(dw, sw, dwt, swt);

  const int n_inc = nf * 3;
  k_fill<<<(n_inc + 255) / 256, 256, 0, stream>>>(face, vt_map, cnt, slots, n_inc);

  const int ntiles_f = (nf + FT - 1) / FT;   // 3125 (one tile per block)
  k_faceg<<<ntiles_f, 256, 0, stream>>>(inputs, fc, swt, dwt, g);

  const int ntiles_v = (nv + 15) / 16;       // 6250
  k_gather<<<GB, 256, 0, stream>>>(g, cnt, slots, nf_cnt, bias, out, part, nv, ntiles_v);

  k_red<<<256, 256, 0, stream>>>(part, red);
  k_fin<<<1, 128, 0, stream>>>(red, gamma, beta, scale, shift, 1.0f / (float)nv);

  const int n4 = (nv * C_OUT) / 4;
  k_bn<<<4096, 256, 0, stream>>>(out, scale, shift, n4);
}

// Round 11
// 159.497 us; speedup vs baseline: 1.1317x; 1.0834x over previous
//
#include <hip/hip_runtime.h>
#include <hip/hip_bf16.h>

// F2VConv3d: per-face double-GEMM (both on MFMA) then lightweight vertex gather.
//   W[f,:] = fc[f,:] @ sw          (MFMA1, K=16 padded to 32, computed as W^T)
//   feat[f,cm] = inp[f,cm>>1] * W[f,cm]   (epilogue: LDS in-place overwrite)
//   g[f] = feat[f,:] @ dw          (MFMA2)
//   out[v] = BN(relu(mean_{f in N(v)} g[f] + bias))
// R10: inp streamed via global_load_lds DMA (16B/lane, no VGPR round-trip,
// 32KB in flight per block — R7/R8/R9 were all stuck ~81us on in-flight-bytes:
// scattered 8B loads + VGPR 52 => ~1.3TB/s eff). Source-swizzled DMA
// (chunk ^= row&7, T21) + pitch-512 LDS; feat bf16 overwrites inp f32
// in place (same thread, same bytes). s_buf = 32KB only.

constexpr int C_IN  = 128;
constexpr int KF    = 16;
constexpr int CM    = 256;    // C_IN * MULT
constexpr int C_OUT = 128;
constexpr int CAP   = 32;     // max tracked faces per vertex
constexpr int GB    = 1024;   // k_gather grid (k_red loops over GB)
constexpr int FT    = 64;     // faces per k_faceg tile
constexpr float BN_EPS = 1e-3f;

typedef __attribute__((ext_vector_type(8))) short short8;
typedef __attribute__((ext_vector_type(4))) float f32x4;

__device__ __forceinline__ ushort f2bf(float x) {
  union { float f; unsigned u; } v; v.f = x;
  return (ushort)((v.u + 0x7fffu + ((v.u >> 16) & 1u)) >> 16);
}
__device__ __forceinline__ float b2f(ushort u) {
  return __uint_as_float((unsigned)u << 16);
}
// packed RNE f32x2 -> bf16x2; low 16 bits = a
__device__ __forceinline__ uint pk2(float a, float b) {
  __hip_bfloat162 h = __float22bfloat162_rn(float2{a, b});
  return *(uint*)&h;
}
// async global->LDS DMA, 16B per lane (dest = wave-uniform base + lane*16)
__device__ __forceinline__ void dma16(const float* g, void* l) {
  __builtin_amdgcn_global_load_lds(
      (const __attribute__((address_space(1))) void*)g,
      (__attribute__((address_space(3))) void*)l, 16, 0, 0);
}

// dwt[n][k] = bf16(dw[k][n]) (MFMA2 B-frag order);
// swt[cm][k] = bf16(sw[k][cm]) padded K 16->32 (MFMA1 A-frag order).
__global__ __launch_bounds__(256) void k_prep(const float* __restrict__ dw,
                                              const float* __restrict__ sw,
                                              ushort* __restrict__ dwt,
                                              ushort* __restrict__ swt) {
  const int b = blockIdx.x, tid = threadIdx.x;
  if (b < 64) {                       // dwt: 128*256 elems, 2/thread
    int i = b * 512 + tid;
#pragma unroll
    for (int r = 0; r < 2; ++r, i += 256) {
      int n = i >> 8, k = i & 255;
      dwt[i] = f2bf(dw[k * C_OUT + n]);
    }
  } else {                            // swt: 256*32 elems, 1/thread
    int i = (b - 64) * 256 + tid;
    int cm = i >> 5, k = i & 31;
    swt[i] = (k < KF) ? f2bf(sw[k * CM + cm]) : (ushort)0;
  }
}

__global__ __launch_bounds__(256) void k_fill(
    const int* __restrict__ face, const int* __restrict__ vt_map,
    int* __restrict__ cnt, int* __restrict__ slots, int n_inc) {
  int i = blockIdx.x * blockDim.x + threadIdx.x;
  if (i < n_inc) {
    int f = i / 3;
    int v = vt_map[face[i]];
    int p = atomicAdd(&cnt[v], 1);
    if (p < CAP) slots[(size_t)v * CAP + p] = f;
  }
}

// One 64-face tile per block, 4 waves.
// LDS s_buf (32KB, pitch 512B/row, XOR-swizzled chunk^=row&7) lifecycle:
//   inp f32 (DMA'd) -> feat bf16 (in-place) -> f32 out staging.
__global__ __launch_bounds__(256, 4) void k_faceg(
    const float* __restrict__ inp, const float* __restrict__ fc,
    const ushort* __restrict__ swt, const ushort* __restrict__ dwt,
    ushort* __restrict__ g) {
  __shared__ __align__(1024) ushort s_buf[FT * 256];   // 32768 B
  char* s_bytes = (char*)s_buf;

  const int tid  = threadIdx.x;
  const int w    = tid >> 6;        // wave -> cm range [w*64, w*64+64)
  const int lane = tid & 63;
  const int rm   = lane & 15;
  const int kg   = lane >> 4;
  const int fb   = blockIdx.x * FT;

  // DMA inp tile: wave w streams rows w*16..w*16+15 (8KB) in 8x 1KB chunks.
  // LDS[row][chunk] = global[row][chunk ^ (row&7)]  (16B chunks, 32/row)
#pragma unroll
  for (int it = 0; it < 8; ++it) {
    const int row   = w * 16 + it * 2 + (lane >> 5);
    const int chunk = lane & 31;
    const float* src = inp + (size_t)(fb + row) * C_IN + ((chunk ^ (row & 7)) << 2);
    dma16(src, s_bytes + w * 8192 + it * 1024);
  }

  // MFMA1 A-frags: swt rows cm = w*64 + ct*16 + rm
  short8 a1[4];
#pragma unroll
  for (int ct = 0; ct < 4; ++ct)
    a1[ct] = *(const short8*)&swt[(size_t)(w * 64 + ct * 16 + rm) * 32 + kg * 8];

  // MFMA1 B-frags from fc (f32 global -> bf16 regs); kg>=2 lanes zero (K-pad)
  short8 b1[4];
#pragma unroll
  for (int ft = 0; ft < 4; ++ft) {
    const float* fr = &fc[(size_t)(fb + ft * 16 + rm) * KF + (kg & 1) * 8];
    const float4 p0 = *(const float4*)fr;
    const float4 p1 = *(const float4*)(fr + 4);
    uint4 u;
    u.x = pk2(p0.x, p0.y); u.y = pk2(p0.z, p0.w);
    u.z = pk2(p1.x, p1.y); u.w = pk2(p1.z, p1.w);
    if (kg >= 2) u = uint4{0, 0, 0, 0};
    b1[ft] = *(short8*)&u;
  }

  asm volatile("s_waitcnt vmcnt(0)" ::: "memory");
  __syncthreads();                  // 0: inp tile in LDS

  // MFMA1 + epilogue: read inp f32 pair from LDS, multiply, overwrite with
  // feat bf16 IN PLACE (same bytes, same thread).
  // D layout (m89): col = lane&15 = face_local, row = kg*4+r = cm_local
#pragma unroll
  for (int ft = 0; ft < 4; ++ft) {
#pragma unroll
    for (int ct = 0; ct < 4; ++ct) {
      f32x4 acc = {0.f, 0.f, 0.f, 0.f};
      acc = __builtin_amdgcn_mfma_f32_16x16x32_bf16(a1[ct], b1[ft], acc, 0, 0, 0);
      const int face = ft * 16 + rm;
      const int cmb  = w * 64 + ct * 16 + kg * 4;       // multiple of 4
      const int byt  = face * 512 + ((((cmb * 2) >> 4) ^ (face & 7)) << 4)
                     + ((cmb * 2) & 15);
      const float2 ivv = *(const float2*)(s_bytes + byt);  // channels cmb>>1, +1
      uint2 pw;
      pw.x = pk2(acc[0] * ivv.x, acc[1] * ivv.x);
      pw.y = pk2(acc[2] * ivv.y, acc[3] * ivv.y);
      *(uint2*)(s_bytes + byt) = pw;                       // feat bf16 in place
    }
  }

  // MFMA2 B-frags (dwt, L2-hot), short live range
  short8 bfr[2][8];
#pragma unroll
  for (int nt = 0; nt < 2; ++nt) {
    const int n = (w * 2 + nt) * 16 + rm;
#pragma unroll
    for (int ks = 0; ks < 8; ++ks)
      bfr[nt][ks] = *(const short8*)&dwt[n * 256 + ks * 32 + kg * 8];
  }
  __syncthreads();                  // 1: feat ready

  f32x4 acc2[4][2];
#pragma unroll
  for (int fs = 0; fs < 4; ++fs)
#pragma unroll
    for (int nt = 0; nt < 2; ++nt)
      acc2[fs][nt] = (f32x4){0.f, 0.f, 0.f, 0.f};

#pragma unroll
  for (int fs = 0; fs < 4; ++fs)
#pragma unroll
    for (int ks = 0; ks < 8; ++ks) {
      const int row = fs * 16 + rm;
      const int byt = row * 512 + (((ks * 4 + kg) ^ (row & 7)) << 4);
      const short8 af = *(const short8*)(s_bytes + byt);
      acc2[fs][0] = __builtin_amdgcn_mfma_f32_16x16x32_bf16(af, bfr[0][ks], acc2[fs][0], 0, 0, 0);
      acc2[fs][1] = __builtin_amdgcn_mfma_f32_16x16x32_bf16(af, bfr[1][ks], acc2[fs][1], 0, 0, 0);
    }
  __syncthreads();                  // 2: all feat reads done (alias!)

  // f32 staging into same 32KB, same swizzle
#pragma unroll
  for (int fs = 0; fs < 4; ++fs)
#pragma unroll
    for (int nt = 0; nt < 2; ++nt)
#pragma unroll
      for (int r = 0; r < 4; ++r) {
        const int row = fs * 16 + kg * 4 + r;
        const int col = (w * 2 + nt) * 16 + rm;
        const int byt = row * 512 + (((col >> 2) ^ (row & 7)) << 4) + (col & 3) * 4;
        *(float*)(s_bytes + byt) = acc2[fs][nt][r];
      }
  __syncthreads();                  // 3: staging ready

  // packed bf16 g stores: thread -> 1/4 row (32 channels)
  const int irow = tid >> 2;
  const int cb   = (tid & 3) * 32;
#pragma unroll
  for (int i = 0; i < 4; ++i) {
    const int c0 = (cb + 8 * i) >> 2;         // chunk of first float4
    const float4 a = *(const float4*)(s_bytes + irow * 512 + ((c0 ^ (irow & 7)) << 4));
    const float4 b = *(const float4*)(s_bytes + irow * 512 + (((c0 + 1) ^ (irow & 7)) << 4));
    uint4 u;
    u.x = pk2(a.x, a.y); u.y = pk2(a.z, a.w);
    u.z = pk2(b.x, b.y); u.w = pk2(b.z, b.w);
    *(short8*)&g[(size_t)(fb + irow) * C_OUT + cb + 8 * i] = *(short8*)&u;
  }
}

// 16 verts/tile, 16 threads/vert, NO per-tile LDS/barriers: slots & cnt read
// via 16-lane broadcast, int4 slot quads, 4-deep g-row load ILP.
__global__ __launch_bounds__(256) void k_gather(
    const ushort* __restrict__ g, const int* __restrict__ cnt,
    const int* __restrict__ slots, const int* __restrict__ nf_cnt,
    const float* __restrict__ bias, float* __restrict__ out,
    float* __restrict__ part, int nv, int ntiles) {
  __shared__ float s_red[256][8];

  const int tid = threadIdx.x;
  const int q   = tid & 15;
  const int vg  = tid >> 4;
  const int c8  = q * 8;

  float bs[8];
#pragma unroll
  for (int j = 0; j < 8; ++j) bs[j] = bias[c8 + j];
  float st_s[8], st_q[8];
#pragma unroll
  for (int j = 0; j < 8; ++j) { st_s[j] = 0.f; st_q[j] = 0.f; }

  for (int tile = blockIdx.x; tile < ntiles; tile += gridDim.x) {
    const int v = tile * 16 + vg;
    int deg = cnt[v]; deg = deg > CAP ? CAP : deg;      // lane-broadcast
    const int* sl = &slots[(size_t)v * CAP];

    float a[8];
#pragma unroll
    for (int j = 0; j < 8; ++j) a[j] = 0.f;

    int t = 0;
    for (; t + 4 <= deg; t += 4) {
      const int4 ff = *(const int4*)&sl[t];             // broadcast 16B
      const short8 r0 = *(const short8*)&g[(size_t)ff.x * C_OUT + c8];
      const short8 r1 = *(const short8*)&g[(size_t)ff.y * C_OUT + c8];
      const short8 r2 = *(const short8*)&g[(size_t)ff.z * C_OUT + c8];
      const short8 r3 = *(const short8*)&g[(size_t)ff.w * C_OUT + c8];
#pragma unroll
      for (int j = 0; j < 8; ++j)
        a[j] += (b2f((ushort)r0[j]) + b2f((ushort)r1[j]))
              + (b2f((ushort)r2[j]) + b2f((ushort)r3[j]));
    }
    for (; t < deg; ++t) {
      const short8 r0 = *(const short8*)&g[(size_t)sl[t] * C_OUT + c8];
#pragma unroll
      for (int j = 0; j < 8; ++j) a[j] += b2f((ushort)r0[j]);
    }

    int d = nf_cnt[v]; if (d < 1) d = 1;
    const float inv = 1.0f / (float)d;
    float r[8];
#pragma unroll
    for (int j = 0; j < 8; ++j) {
      r[j] = fmaxf(fmaf(a[j], inv, bs[j]), 0.f);
      st_s[j] += r[j];
      st_q[j] = fmaf(r[j], r[j], st_q[j]);
    }
    *(float4*)&out[(size_t)v * C_OUT + c8]     = make_float4(r[0], r[1], r[2], r[3]);
    *(float4*)&out[(size_t)v * C_OUT + c8 + 4] = make_float4(r[4], r[5], r[6], r[7]);
  }

  // deterministic block partials: part[col][GB] (transposed)
#pragma unroll
  for (int j = 0; j < 8; ++j) s_red[tid][j] = st_s[j];
  __syncthreads();
  if (tid < 16) {
    for (int j = 0; j < 8; ++j) {
      float x = 0.f;
      for (int gg = 0; gg < 16; ++gg) x += s_red[gg * 16 + tid][j];
      part[(size_t)(tid * 8 + j) * GB + blockIdx.x] = x;
    }
  }
  __syncthreads();
#pragma unroll
  for (int j = 0; j < 8; ++j) s_red[tid][j] = st_q[j];
  __syncthreads();
  if (tid < 16) {
    for (int j = 0; j < 8; ++j) {
      float x = 0.f;
      for (int gg = 0; gg < 16; ++gg) x += s_red[gg * 16 + tid][j];
      part[(size_t)(128 + tid * 8 + j) * GB + blockIdx.x] = x;
    }
  }
}

// 256 blocks: block j reduces part[j][0:GB] (coalesced) -> red[j].
__global__ __launch_bounds__(256) void k_red(const float* __restrict__ part,
                                             float* __restrict__ red) {
  const int j   = blockIdx.x;
  const int tid = threadIdx.x;
  float v = 0.f;
#pragma unroll
  for (int b = 0; b < GB; b += 256) v += part[(size_t)j * GB + b + tid];
#pragma unroll
  for (int off = 32; off > 0; off >>= 1) v += __shfl_down(v, off);
  __shared__ float sred[4];
  if ((tid & 63) == 0) sred[tid >> 6] = v;
  __syncthreads();
  if (tid == 0) red[j] = sred[0] + sred[1] + sred[2] + sred[3];
}

__global__ void k_fin(const float* __restrict__ red,
                      const float* __restrict__ gamma, const float* __restrict__ beta,
                      float* __restrict__ scale, float* __restrict__ shift, float invN) {
  int o = threadIdx.x;   // 128
  float mean = red[o] * invN;
  float var  = red[128 + o] * invN - mean * mean;
  float sc   = gamma[o] * rsqrtf(var + BN_EPS);
  scale[o] = sc;
  shift[o] = fmaf(-mean, sc, beta[o]);
}

__global__ __launch_bounds__(256) void k_bn(float* __restrict__ out,
                                            const float* __restrict__ scale,
                                            const float* __restrict__ shift, int n4) {
  int idx = blockIdx.x * blockDim.x + threadIdx.x;
  int stride = gridDim.x * blockDim.x;
  for (; idx < n4; idx += stride) {
    float4 v = ((const float4*)out)[idx];
    int base = (idx * 4) & (C_OUT - 1);
    float4 sc = *(const float4*)&scale[base];
    float4 sh = *(const float4*)&shift[base];
    v.x = fmaf(v.x, sc.x, sh.x);
    v.y = fmaf(v.y, sc.y, sh.y);
    v.z = fmaf(v.z, sc.z, sh.z);
    v.w = fmaf(v.w, sc.w, sh.w);
    ((float4*)out)[idx] = v;
  }
}

extern "C" void kernel_launch(void* const* d_in, const int* in_sizes, int n_in,
                              void* d_out, int out_size, void* d_ws, size_t ws_size,
                              hipStream_t stream) {
  const float* inputs = (const float*)d_in[0];
  const float* fc     = (const float*)d_in[1];
  const int*   face   = (const int*)d_in[2];
  const int*   nf_cnt = (const int*)d_in[3];
  const int*   vt_map = (const int*)d_in[4];
  const float* sw     = (const float*)d_in[5];
  const float* dw     = (const float*)d_in[6];
  const float* bias   = (const float*)d_in[7];
  const float* gamma  = (const float*)d_in[8];
  const float* beta   = (const float*)d_in[9];
  float* out = (float*)d_out;

  const int nf = in_sizes[0] / C_IN;   // 200000
  const int nv = in_sizes[3];          // 100000

  // ws: cnt[nv] | scale[128] | shift[128] | red[256] | part[256*GB]
  //     | dwt[128*256 u16] | swt[256*32 u16] | slots[nv*CAP] | g[nf*128 u16]
  char* p = (char*)d_ws;
  int*    cnt   = (int*)p;            p += (size_t)nv * 4;
  float*  scale = (float*)p;          p += C_OUT * 4;
  float*  shift = (float*)p;          p += C_OUT * 4;
  float*  red   = (float*)p;          p += 256 * 4;
  float*  part  = (float*)p;          p += (size_t)256 * GB * 4;
  ushort* dwt   = (ushort*)p;         p += (size_t)C_OUT * CM * 2;
  ushort* swt   = (ushort*)p;         p += (size_t)CM * 32 * 2;
  int*    slots = (int*)p;            p += (size_t)nv * CAP * 4;
  ushort* g     = (ushort*)p;

  hipMemsetAsync(cnt, 0, (size_t)nv * 4, stream);

  k_prep<<<96, 256, 0, stream>>>(dw, sw, dwt, swt);

  const int n_inc = nf * 3;
  k_fill<<<(n_inc + 255) / 256, 256, 0, stream>>>(face, vt_map, cnt, slots, n_inc);

  const int ntiles_f = (nf + FT - 1) / FT;   // 3125 (one tile per block)
  k_faceg<<<ntiles_f, 256, 0, stream>>>(inputs, fc, swt, dwt, g);

  const int ntiles_v = (nv + 15) / 16;       // 6250
  k_gather<<<GB, 256, 0, stream>>>(g, cnt, slots, nf_cnt, bias, out, part, nv, ntiles_v);

  k_red<<<256, 256, 0, stream>>>(part, red);
  k_fin<<<1, 128, 0, stream>>>(red, gamma, beta, scale, shift, 1.0f / (float)nv);

  const int n4 = (nv * C_OUT) / 4;
  k_bn<<<4096, 256, 0, stream>>>(out, scale, shift, n4);
}

// Round 12
// 150.433 us; speedup vs baseline: 1.1999x; 1.0603x over previous
//
#include <hip/hip_runtime.h>
#include <hip/hip_bf16.h>

// F2VConv3d: per-face double-GEMM (both on MFMA) then lightweight vertex gather.
//   W[f,:] = fc[f,:] @ sw          (MFMA1, K=16 padded to 32, computed as W^T)
//   feat[f,cm] = inp[f,cm>>1] * W[f,cm]   (epilogue: LDS in-place overwrite)
//   g[f] = feat[f,:] @ dw          (MFMA2)
//   out[v] = BN(relu(mean_{f in N(v)} g[f] + bias))
// R11: k_faceg pipelined across tiles (T3/T4): grid=512 persistent, 2x32KB
// LDS double-buffer, next tile's DMA issued BEFORE current compute, counted
// s_waitcnt vmcnt(8) (never 0 mid-loop), raw s_barrier + lgkmcnt(0) instead
// of __syncthreads (avoids the compiler's vmcnt(0)-before-barrier drain that
// serialized R8-R10 at ~75-85us). dwt/swt frags hoisted loop-invariant
// (launch_bounds(256,2) -> 256 VGPR budget). g-store staging-read bank
// conflict fixed (chunk pairs 2q+8i).

constexpr int C_IN  = 128;
constexpr int KF    = 16;
constexpr int CM    = 256;    // C_IN * MULT
constexpr int C_OUT = 128;
constexpr int CAP   = 32;     // max tracked faces per vertex
constexpr int GB    = 1024;   // k_gather grid (k_red loops over GB)
constexpr int FT    = 64;     // faces per k_faceg tile
constexpr int GRIDF = 512;    // k_faceg grid (2 blocks/CU with 64KB LDS)
constexpr float BN_EPS = 1e-3f;

typedef __attribute__((ext_vector_type(8))) short short8;
typedef __attribute__((ext_vector_type(4))) float f32x4;

__device__ __forceinline__ ushort f2bf(float x) {
  union { float f; unsigned u; } v; v.f = x;
  return (ushort)((v.u + 0x7fffu + ((v.u >> 16) & 1u)) >> 16);
}
__device__ __forceinline__ float b2f(ushort u) {
  return __uint_as_float((unsigned)u << 16);
}
// packed RNE f32x2 -> bf16x2; low 16 bits = a
__device__ __forceinline__ uint pk2(float a, float b) {
  __hip_bfloat162 h = __float22bfloat162_rn(float2{a, b});
  return *(uint*)&h;
}
// async global->LDS DMA, 16B per lane (dest = wave-uniform base + lane*16)
__device__ __forceinline__ void dma16(const float* g, void* l) {
  __builtin_amdgcn_global_load_lds(
      (const __attribute__((address_space(1))) void*)g,
      (__attribute__((address_space(3))) void*)l, 16, 0, 0);
}
// raw barrier (no implicit vmcnt drain) + compiler memory fence
__device__ __forceinline__ void bar_raw() {
  __builtin_amdgcn_s_barrier();
  asm volatile("" ::: "memory");
}
__device__ __forceinline__ void bar_lds() {
  asm volatile("s_waitcnt lgkmcnt(0)" ::: "memory");
  __builtin_amdgcn_s_barrier();
  asm volatile("" ::: "memory");
}

// dwt[n][k] = bf16(dw[k][n]) (MFMA2 B-frag order);
// swt[cm][k] = bf16(sw[k][cm]) padded K 16->32 (MFMA1 A-frag order).
__global__ __launch_bounds__(256) void k_prep(const float* __restrict__ dw,
                                              const float* __restrict__ sw,
                                              ushort* __restrict__ dwt,
                                              ushort* __restrict__ swt) {
  const int b = blockIdx.x, tid = threadIdx.x;
  if (b < 64) {                       // dwt: 128*256 elems, 2/thread
    int i = b * 512 + tid;
#pragma unroll
    for (int r = 0; r < 2; ++r, i += 256) {
      int n = i >> 8, k = i & 255;
      dwt[i] = f2bf(dw[k * C_OUT + n]);
    }
  } else {                            // swt: 256*32 elems, 1/thread
    int i = (b - 64) * 256 + tid;
    int cm = i >> 5, k = i & 31;
    swt[i] = (k < KF) ? f2bf(sw[k * CM + cm]) : (ushort)0;
  }
}

__global__ __launch_bounds__(256) void k_fill(
    const int* __restrict__ face, const int* __restrict__ vt_map,
    int* __restrict__ cnt, int* __restrict__ slots, int n_inc) {
  int i = blockIdx.x * blockDim.x + threadIdx.x;
  if (i < n_inc) {
    int f = i / 3;
    int v = vt_map[face[i]];
    int p = atomicAdd(&cnt[v], 1);
    if (p < CAP) slots[(size_t)v * CAP + p] = f;
  }
}

// Persistent pipelined k_faceg. Per tile: [TOP bar] [fc loads, prefetch-DMA
// next tile] [vmcnt(8)] [build b1] [bar A] [MFMA1+epi in-place] [bar B]
// [MFMA2] [bar C] [f32 staging] [bar D] [g stores].
__global__ __launch_bounds__(256, 2) void k_faceg(
    const float* __restrict__ inp, const float* __restrict__ fc,
    const ushort* __restrict__ swt, const ushort* __restrict__ dwt,
    ushort* __restrict__ g, int ntiles) {
  __shared__ __align__(1024) ushort s_buf[2][FT * 256];   // 2 x 32768 B

  const int tid  = threadIdx.x;
  const int w    = tid >> 6;        // wave -> cm range [w*64, w*64+64)
  const int lane = tid & 63;
  const int rm   = lane & 15;
  const int kg   = lane >> 4;

  // loop-invariant fragments (budget: launch_bounds(256,2) -> 256 VGPR)
  short8 a1[4];
#pragma unroll
  for (int ct = 0; ct < 4; ++ct)
    a1[ct] = *(const short8*)&swt[(size_t)(w * 64 + ct * 16 + rm) * 32 + kg * 8];
  short8 bfr[2][8];
#pragma unroll
  for (int nt = 0; nt < 2; ++nt) {
    const int n = (w * 2 + nt) * 16 + rm;
#pragma unroll
    for (int ks = 0; ks < 8; ++ks)
      bfr[nt][ks] = *(const short8*)&dwt[n * 256 + ks * 32 + kg * 8];
  }

  // DMA one 64-face inp tile (32KB) into buffer `buf`, source-swizzled
  // (LDS[row][chunk] = global[row][chunk ^ (row&7)], 16B chunks).
  auto issue_dma = [&](int buf, int fb) {
#pragma unroll
    for (int it = 0; it < 8; ++it) {
      const int row   = w * 16 + it * 2 + (lane >> 5);
      const int chunk = lane & 31;
      const float* src = inp + (size_t)(fb + row) * C_IN + ((chunk ^ (row & 7)) << 2);
      dma16(src, (char*)s_buf + buf * 32768 + w * 8192 + it * 1024);
    }
  };

  int t = blockIdx.x;
  issue_dma(0, t * FT);              // prologue: tile t0 in flight
  int cur = 0;

  for (; t < ntiles; t += GRIDF, cur ^= 1) {
    const int fb = t * FT;
    char* sb = (char*)s_buf + cur * 32768;

    // TOP: previous iter's LDS reads drained before prefetch lands in other buf
    bar_lds();

    // fc loads for current tile (8x dwordx4)
    float4 p0[4], p1[4];
#pragma unroll
    for (int ft = 0; ft < 4; ++ft) {
      const float* fr = &fc[(size_t)(fb + ft * 16 + rm) * KF + (kg & 1) * 8];
      p0[ft] = *(const float4*)fr;
      p1[ft] = *(const float4*)(fr + 4);
    }

    // prefetch next tile's DMA, then counted wait: retires current tile's
    // DMA + fc, leaves next tile's 8 DMA in flight across all barriers.
    const int tn = t + GRIDF;
    if (tn < ntiles) {
      issue_dma(cur ^ 1, tn * FT);
      asm volatile("s_waitcnt vmcnt(8)" ::: "memory");
    } else {
      asm volatile("s_waitcnt vmcnt(0)" ::: "memory");
    }

    // build MFMA1 B-frags (kg>=2 lanes zero: K padded 16->32)
    short8 b1[4];
#pragma unroll
    for (int ft = 0; ft < 4; ++ft) {
      uint4 u;
      u.x = pk2(p0[ft].x, p0[ft].y); u.y = pk2(p0[ft].z, p0[ft].w);
      u.z = pk2(p1[ft].x, p1[ft].y); u.w = pk2(p1[ft].z, p1[ft].w);
      if (kg >= 2) u = uint4{0, 0, 0, 0};
      b1[ft] = *(short8*)&u;
    }

    bar_raw();                        // A: buf[cur] fully DMA'd (all waves)

    // MFMA1 + epilogue: read inp f32 pair from LDS, multiply, overwrite with
    // feat bf16 IN PLACE. D layout (m89): col=lane&15=face, row=kg*4+r=cm.
#pragma unroll
    for (int ft = 0; ft < 4; ++ft) {
#pragma unroll
      for (int ct = 0; ct < 4; ++ct) {
        f32x4 acc = {0.f, 0.f, 0.f, 0.f};
        acc = __builtin_amdgcn_mfma_f32_16x16x32_bf16(a1[ct], b1[ft], acc, 0, 0, 0);
        const int face = ft * 16 + rm;
        const int cmb  = w * 64 + ct * 16 + kg * 4;     // multiple of 4
        const int byt  = face * 512 + ((((cmb * 2) >> 4) ^ (face & 7)) << 4)
                       + ((cmb * 2) & 15);
        const float2 ivv = *(const float2*)(sb + byt);
        uint2 pw;
        pw.x = pk2(acc[0] * ivv.x, acc[1] * ivv.x);
        pw.y = pk2(acc[2] * ivv.y, acc[3] * ivv.y);
        *(uint2*)(sb + byt) = pw;
      }
    }

    bar_lds();                        // B: feat ready

    f32x4 acc2[4][2];
#pragma unroll
    for (int fs = 0; fs < 4; ++fs)
#pragma unroll
      for (int nt = 0; nt < 2; ++nt)
        acc2[fs][nt] = (f32x4){0.f, 0.f, 0.f, 0.f};

#pragma unroll
    for (int fs = 0; fs < 4; ++fs)
#pragma unroll
      for (int ks = 0; ks < 8; ++ks) {
        const int row = fs * 16 + rm;
        const int byt = row * 512 + (((ks * 4 + kg) ^ (row & 7)) << 4);
        const short8 af = *(const short8*)(sb + byt);
        acc2[fs][0] = __builtin_amdgcn_mfma_f32_16x16x32_bf16(af, bfr[0][ks], acc2[fs][0], 0, 0, 0);
        acc2[fs][1] = __builtin_amdgcn_mfma_f32_16x16x32_bf16(af, bfr[1][ks], acc2[fs][1], 0, 0, 0);
      }

    bar_lds();                        // C: all feat reads done (alias!)

    // f32 staging into same buffer, same swizzle
#pragma unroll
    for (int fs = 0; fs < 4; ++fs)
#pragma unroll
      for (int nt = 0; nt < 2; ++nt)
#pragma unroll
        for (int r = 0; r < 4; ++r) {
          const int row = fs * 16 + kg * 4 + r;
          const int col = (w * 2 + nt) * 16 + rm;
          const int byt = row * 512 + (((col >> 2) ^ (row & 7)) << 4) + (col & 3) * 4;
          *(float*)(sb + byt) = acc2[fs][nt][r];
        }

    bar_lds();                        // D: staging ready

    // packed bf16 g stores: thread (row=tid>>2, q=tid&3) reads chunk pairs
    // {2q+8i, 2q+1+8i} (distinct banks mod 8 across q) -> channels 8q+32i..+7
    const int irow = tid >> 2;
    const int q    = tid & 3;
#pragma unroll
    for (int i = 0; i < 4; ++i) {
      const int c0 = 2 * q + 8 * i;
      const float4 a = *(const float4*)(sb + irow * 512 + ((c0 ^ (irow & 7)) << 4));
      const float4 b = *(const float4*)(sb + irow * 512 + (((c0 + 1) ^ (irow & 7)) << 4));
      uint4 u;
      u.x = pk2(a.x, a.y); u.y = pk2(a.z, a.w);
      u.z = pk2(b.x, b.y); u.w = pk2(b.z, b.w);
      *(short8*)&g[(size_t)(fb + irow) * C_OUT + c0 * 4] = *(short8*)&u;
    }
  }
}

// 16 verts/tile, 16 threads/vert, NO per-tile LDS/barriers: slots & cnt read
// via 16-lane broadcast, int4 slot quads, 4-deep g-row load ILP.
__global__ __launch_bounds__(256) void k_gather(
    const ushort* __restrict__ g, const int* __restrict__ cnt,
    const int* __restrict__ slots, const int* __restrict__ nf_cnt,
    const float* __restrict__ bias, float* __restrict__ out,
    float* __restrict__ part, int nv, int ntiles) {
  __shared__ float s_red[256][8];

  const int tid = threadIdx.x;
  const int q   = tid & 15;
  const int vg  = tid >> 4;
  const int c8  = q * 8;

  float bs[8];
#pragma unroll
  for (int j = 0; j < 8; ++j) bs[j] = bias[c8 + j];
  float st_s[8], st_q[8];
#pragma unroll
  for (int j = 0; j < 8; ++j) { st_s[j] = 0.f; st_q[j] = 0.f; }

  for (int tile = blockIdx.x; tile < ntiles; tile += gridDim.x) {
    const int v = tile * 16 + vg;
    int deg = cnt[v]; deg = deg > CAP ? CAP : deg;      // lane-broadcast
    const int* sl = &slots[(size_t)v * CAP];

    float a[8];
#pragma unroll
    for (int j = 0; j < 8; ++j) a[j] = 0.f;

    int t = 0;
    for (; t + 4 <= deg; t += 4) {
      const int4 ff = *(const int4*)&sl[t];             // broadcast 16B
      const short8 r0 = *(const short8*)&g[(size_t)ff.x * C_OUT + c8];
      const short8 r1 = *(const short8*)&g[(size_t)ff.y * C_OUT + c8];
      const short8 r2 = *(const short8*)&g[(size_t)ff.z * C_OUT + c8];
      const short8 r3 = *(const short8*)&g[(size_t)ff.w * C_OUT + c8];
#pragma unroll
      for (int j = 0; j < 8; ++j)
        a[j] += (b2f((ushort)r0[j]) + b2f((ushort)r1[j]))
              + (b2f((ushort)r2[j]) + b2f((ushort)r3[j]));
    }
    for (; t < deg; ++t) {
      const short8 r0 = *(const short8*)&g[(size_t)sl[t] * C_OUT + c8];
#pragma unroll
      for (int j = 0; j < 8; ++j) a[j] += b2f((ushort)r0[j]);
    }

    int d = nf_cnt[v]; if (d < 1) d = 1;
    const float inv = 1.0f / (float)d;
    float r[8];
#pragma unroll
    for (int j = 0; j < 8; ++j) {
      r[j] = fmaxf(fmaf(a[j], inv, bs[j]), 0.f);
      st_s[j] += r[j];
      st_q[j] = fmaf(r[j], r[j], st_q[j]);
    }
    *(float4*)&out[(size_t)v * C_OUT + c8]     = make_float4(r[0], r[1], r[2], r[3]);
    *(float4*)&out[(size_t)v * C_OUT + c8 + 4] = make_float4(r[4], r[5], r[6], r[7]);
  }

  // deterministic block partials: part[col][GB] (transposed)
#pragma unroll
  for (int j = 0; j < 8; ++j) s_red[tid][j] = st_s[j];
  __syncthreads();
  if (tid < 16) {
    for (int j = 0; j < 8; ++j) {
      float x = 0.f;
      for (int gg = 0; gg < 16; ++gg) x += s_red[gg * 16 + tid][j];
      part[(size_t)(tid * 8 + j) * GB + blockIdx.x] = x;
    }
  }
  __syncthreads();
#pragma unroll
  for (int j = 0; j < 8; ++j) s_red[tid][j] = st_q[j];
  __syncthreads();
  if (tid < 16) {
    for (int j = 0; j < 8; ++j) {
      float x = 0.f;
      for (int gg = 0; gg < 16; ++gg) x += s_red[gg * 16 + tid][j];
      part[(size_t)(128 + tid * 8 + j) * GB + blockIdx.x] = x;
    }
  }
}

// 256 blocks: block j reduces part[j][0:GB] (coalesced) -> red[j].
__global__ __launch_bounds__(256) void k_red(const float* __restrict__ part,
                                             float* __restrict__ red) {
  const int j   = blockIdx.x;
  const int tid = threadIdx.x;
  float v = 0.f;
#pragma unroll
  for (int b = 0; b < GB; b += 256) v += part[(size_t)j * GB + b + tid];
#pragma unroll
  for (int off = 32; off > 0; off >>= 1) v += __shfl_down(v, off);
  __shared__ float sred[4];
  if ((tid & 63) == 0) sred[tid >> 6] = v;
  __syncthreads();
  if (tid == 0) red[j] = sred[0] + sred[1] + sred[2] + sred[3];
}

__global__ void k_fin(const float* __restrict__ red,
                      const float* __restrict__ gamma, const float* __restrict__ beta,
                      float* __restrict__ scale, float* __restrict__ shift, float invN) {
  int o = threadIdx.x;   // 128
  float mean = red[o] * invN;
  float var  = red[128 + o] * invN - mean * mean;
  float sc   = gamma[o] * rsqrtf(var + BN_EPS);
  scale[o] = sc;
  shift[o] = fmaf(-mean, sc, beta[o]);
}

__global__ __launch_bounds__(256) void k_bn(float* __restrict__ out,
                                            const float* __restrict__ scale,
                                            const float* __restrict__ shift, int n4) {
  int idx = blockIdx.x * blockDim.x + threadIdx.x;
  int stride = gridDim.x * blockDim.x;
  for (; idx < n4; idx += stride) {
    float4 v = ((const float4*)out)[idx];
    int base = (idx * 4) & (C_OUT - 1);
    float4 sc = *(const float4*)&scale[base];
    float4 sh = *(const float4*)&shift[base];
    v.x = fmaf(v.x, sc.x, sh.x);
    v.y = fmaf(v.y, sc.y, sh.y);
    v.z = fmaf(v.z, sc.z, sh.z);
    v.w = fmaf(v.w, sc.w, sh.w);
    ((float4*)out)[idx] = v;
  }
}

extern "C" void kernel_launch(void* const* d_in, const int* in_sizes, int n_in,
                              void* d_out, int out_size, void* d_ws, size_t ws_size,
                              hipStream_t stream) {
  const float* inputs = (const float*)d_in[0];
  const float* fc     = (const float*)d_in[1];
  const int*   face   = (const int*)d_in[2];
  const int*   nf_cnt = (const int*)d_in[3];
  const int*   vt_map = (const int*)d_in[4];
  const float* sw     = (const float*)d_in[5];
  const float* dw     = (const float*)d_in[6];
  const float* bias   = (const float*)d_in[7];
  const float* gamma  = (const float*)d_in[8];
  const float* beta   = (const float*)d_in[9];
  float* out = (float*)d_out;

  const int nf = in_sizes[0] / C_IN;   // 200000
  const int nv = in_sizes[3];          // 100000

  // ws: cnt[nv] | scale[128] | shift[128] | red[256] | part[256*GB]
  //     | dwt[128*256 u16] | swt[256*32 u16] | slots[nv*CAP] | g[nf*128 u16]
  char* p = (char*)d_ws;
  int*    cnt   = (int*)p;            p += (size_t)nv * 4;
  float*  scale = (float*)p;          p += C_OUT * 4;
  float*  shift = (float*)p;          p += C_OUT * 4;
  float*  red   = (float*)p;          p += 256 * 4;
  float*  part  = (float*)p;          p += (size_t)256 * GB * 4;
  ushort* dwt   = (ushort*)p;         p += (size_t)C_OUT * CM * 2;
  ushort* swt   = (ushort*)p;         p += (size_t)CM * 32 * 2;
  int*    slots = (int*)p;            p += (size_t)nv * CAP * 4;
  ushort* g     = (ushort*)p;

  hipMemsetAsync(cnt, 0, (size_t)nv * 4, stream);

  k_prep<<<96, 256, 0, stream>>>(dw, sw, dwt, swt);

  const int n_inc = nf * 3;
  k_fill<<<(n_inc + 255) / 256, 256, 0, stream>>>(face, vt_map, cnt, slots, n_inc);

  const int ntiles_f = (nf + FT - 1) / FT;   // 3125, ~6.1 tiles per block
  k_faceg<<<GRIDF, 256, 0, stream>>>(inputs, fc, swt, dwt, g, ntiles_f);

  const int ntiles_v = (nv + 15) / 16;       // 6250
  k_gather<<<GB, 256, 0, stream>>>(g, cnt, slots, nf_cnt, bias, out, part, nv, ntiles_v);

  k_red<<<256, 256, 0, stream>>>(part, red);
  k_fin<<<1, 128, 0, stream>>>(red, gamma, beta, scale, shift, 1.0f / (float)nv);

  const int n4 = (nv * C_OUT) / 4;
  k_bn<<<4096, 256, 0, stream>>>(out, scale, shift, n4);
}